// Round 1
// baseline (238.782 us; speedup 1.0000x reference)
//
#include <hip/hip_runtime.h>

#define N_NODES 10000
#define N_EDGES 640000
#define D 128

#define GRID 1024          // 4 blocks/CU x 256 CUs, co-residency guaranteed:
                           // LDS 34816*4=139264<=163840, VGPR<=128 via launch_bounds
#define GEMM_BLOCKS 157    // 64 nodes per block (MFMA)
#define SCAT_BLOCKS (GRID - GEMM_BLOCKS)   // 867 dedicated scatter blocks
#define CAP 32             // per-(row,xcd-group) capacity (mean ~8)
#define OVF_CAP 8192
#define LSTR 136           // LDS row stride in ushorts: 272B, 16B-aligned, 2-way banks
#define QPAD 272           // per-wave flat queue: 256 recs + 16 zero pad

typedef unsigned int uint32;
typedef unsigned short u16;
using short8 = __attribute__((ext_vector_type(8))) short;
using f32x4  = __attribute__((ext_vector_type(4))) float;

__device__ __forceinline__ uint32 f2bf_bits(float f) {
    uint32 u = __float_as_uint(f);
    return (u + 0x7FFFu + ((u >> 16) & 1u)) >> 16;   // RNE bf16 bits
}
__device__ __forceinline__ uint32 pack2(float lo, float hi) {
    return f2bf_bits(lo) | (f2bf_bits(hi) << 16);
}

__device__ __forceinline__ void scat_one(int r, uint32 rc, int s,
                                         int* __restrict__ cursor,
                                         uint32* __restrict__ region,
                                         int* ovf_cnt, uint2* ovf)
{
    int pos = atomicAdd(&cursor[s * N_NODES + r], 1);   // group-private cursor
    if (pos < CAP) {
        // region[row][group][CAP]: 128B cell => 64B lines group-exclusive,
        // writes merge in the issuing XCD's L2.
        region[(r * 8 + s) * CAP + pos] = rc;
    } else {                                   // ~never (Poisson(8) tail), correct
        int o = atomicAdd(ovf_cnt, 1);
        if (o < OVF_CAP) ovf[o] = make_uint2((uint32)r, rc);
    }
}

// R9: single fused kernel.
//   Phase A: blocks [0,157) do the MFMA-GEMM tile (h2 = pack_bf16(x@W), direct
//            global->reg A-fragments, W staged col-major in LDS); blocks
//            [157,1024) scatter the edge list into XCD-group capacity regions.
//   Device-wide barrier: fence(agent release: wbL2) -> atomic arrive ->
//            relaxed spin -> fence(agent acquire: invL2). Co-residency of all
//            1024 blocks is guaranteed (see GRID comment), so no deadlock.
//   Phase B: wave-per-row SpMM (identical proven R8 body) over rows
//            gwave, gwave+4096, ... ; LDS queue aliases the Ws buffer.
__global__ __launch_bounds__(256, 4) void fused_kernel(
    const float* __restrict__ x, const float* __restrict__ w,
    const int* __restrict__ row, const int* __restrict__ col,
    const float* __restrict__ val,
    uint32* __restrict__ h2, int* __restrict__ cursor,
    int* __restrict__ ovf_cnt, uint2* __restrict__ ovf,
    uint32* __restrict__ region,
    const float* __restrict__ bias, float* __restrict__ out,
    int* __restrict__ bar)
{
    __shared__ __align__(16) u16 Ws[128 * LSTR];   // 34816 B; phase-B queue alias
    const int t = threadIdx.x;
    const int lane = t & 63;
    const int wid  = t >> 6;

    if (blockIdx.x < GEMM_BLOCKS) {
        // ---- MFMA GEMM: 64 rows/block, 4 waves x 16 rows x 128 cols.
        // A[m=lane&15][k=quad*8+j] loaded DIRECTLY global->reg (no Xs LDS);
        // B mirrors (k-major per lane) => W staged col-major, each frag one
        // 16B LDS read. C/D: col=lane&15, row=quad*4+reg (HW-verified).
        const int q = lane >> 4, cl = lane & 15;

        #pragma unroll
        for (int i = 0; i < 32; ++i) {                // stage W^T (128x128)
            int lin = t + i * 256;                    // k-pair x col index
            int c = lin & 127;
            int m = lin >> 7;
            float w0 = w[(2 * m) * D + c];
            float w1 = w[(2 * m + 1) * D + c];
            *(uint32*)&Ws[c * LSTR + 2 * m] = pack2(w0, w1);
        }

        int gr = blockIdx.x * 64 + wid * 16 + cl;     // A-fragment row
        if (gr >= N_NODES) gr = N_NODES - 1;          // tail clamp (dup, guarded write)
        const float* xrow = &x[(size_t)gr * D];
        float4 xv[8];
        #pragma unroll
        for (int kk = 0; kk < 4; ++kk) {              // 8 fp32 per k-chunk
            xv[2 * kk]     = *(const float4*)&xrow[kk * 32 + q * 8];
            xv[2 * kk + 1] = *(const float4*)&xrow[kk * 32 + q * 8 + 4];
        }
        __syncthreads();

        f32x4 acc[8] = {};
        #pragma unroll
        for (int kk = 0; kk < 4; ++kk) {
            union { short8 s; uint32 u[4]; } af;
            float4 a = xv[2 * kk], b = xv[2 * kk + 1];
            af.u[0] = pack2(a.x, a.y); af.u[1] = pack2(a.z, a.w);
            af.u[2] = pack2(b.x, b.y); af.u[3] = pack2(b.z, b.w);
            #pragma unroll
            for (int ct = 0; ct < 8; ++ct) {
                short8 bf = *(const short8*)&Ws[(ct * 16 + cl) * LSTR + kk * 32 + q * 8];
                acc[ct] = __builtin_amdgcn_mfma_f32_16x16x32_bf16(af.s, bf, acc[ct], 0, 0, 0);
            }
        }
        // h2[node*64 + c] packs cols (c, c+64): same lane holds tiles ct, ct+4.
        #pragma unroll
        for (int reg = 0; reg < 4; ++reg) {
            int node = blockIdx.x * 64 + wid * 16 + q * 4 + reg;
            if (node < N_NODES) {
                uint32* base = h2 + (size_t)node * 64 + cl;
                #pragma unroll
                for (int ct = 0; ct < 4; ++ct)
                    base[ct * 16] = pack2(acc[ct][reg], acc[ct + 4][reg]);
            }
        }
    } else {
        // ---- Scatter: 867 blocks, ~2.9 edges/thread (was ~10 at 256 blocks)
        const int xcc = blockIdx.x & 7;     // round-robin block->XCD locality
        const int tid    = (blockIdx.x - GEMM_BLOCKS) * 256 + t;
        const int stride = SCAT_BLOCKS * 256;
        const int4*   row4 = (const int4*)row;
        const int4*   col4 = (const int4*)col;
        const float4* val4 = (const float4*)val;
        for (int i = tid; i < N_EDGES / 4; i += stride) {
            int4 r = row4[i]; int4 c = col4[i]; float4 v = val4[i];
            scat_one(r.x, (uint32)c.x | (f2bf_bits(v.x) << 16), xcc, cursor, region, ovf_cnt, ovf);
            scat_one(r.y, (uint32)c.y | (f2bf_bits(v.y) << 16), xcc, cursor, region, ovf_cnt, ovf);
            scat_one(r.z, (uint32)c.z | (f2bf_bits(v.z) << 16), xcc, cursor, region, ovf_cnt, ovf);
            scat_one(r.w, (uint32)c.w | (f2bf_bits(v.w) << 16), xcc, cursor, region, ovf_cnt, ovf);
        }
    }

    // ---- device-wide barrier (bar zeroed by host memset each iteration) ----
    __syncthreads();                     // all waves' stores drained to L2
    if (t == 0) {
        __threadfence();                 // agent release: write back dirty L2
        __hip_atomic_fetch_add(bar, 1, __ATOMIC_RELAXED, __HIP_MEMORY_SCOPE_AGENT);
        while (__hip_atomic_load(bar, __ATOMIC_RELAXED, __HIP_MEMORY_SCOPE_AGENT) < GRID)
            __builtin_amdgcn_s_sleep(2); // relaxed spin: no per-iter L2 inv
        __threadfence();                 // agent acquire: invalidate L1/L2
    }
    __syncthreads();

    // ---- Phase B: wave-per-row SpMM (R8 body), rows strided by 4096 waves.
    {
        uint32* qbuf = (uint32*)Ws;                  // alias (4352 B of 34816)
        uint32* qb = &qbuf[wid * QPAD];

        for (int r = blockIdx.x * 4 + wid; r < N_NODES; r += GRID * 4) {
            __builtin_amdgcn_s_waitcnt(0);           // WAR: prior row's qb reads done

            // preload the row's 1KB region block (segment s = cell>>5, pos = cell&31)
            uint32 rl[4];
            #pragma unroll
            for (int i = 0; i < 4; ++i)
                rl[i] = region[r * 256 + i * 64 + lane];

            // counts + prefix (wave-uniform scalars, computed redundantly per lane)
            int ns[8], pref[9];
            pref[0] = 0;
            #pragma unroll
            for (int s = 0; s < 8; ++s) {
                int c = cursor[s * N_NODES + r];
                ns[s] = (c < CAP) ? c : CAP;
                pref[s + 1] = pref[s] + ns[s];
            }
            const int ntot = pref[8];

            // compact valid recs to flat LDS list; chunk i: lanes<32 seg 2i,
            // lanes>=32 seg 2i+1 (pos = lane&31).
            #pragma unroll
            for (int i = 0; i < 4; ++i) {
                int p  = lane & 31;
                int hi = lane >> 5;
                int n_  = hi ? ns[2 * i + 1]   : ns[2 * i];
                int pf  = hi ? pref[2 * i + 1] : pref[2 * i];
                if (p < n_) qb[pf + p] = rl[i];
            }
            if (lane < 16) qb[ntot + lane] = 0;      // zero pad (val=+0.0 recs)
            __builtin_amdgcn_s_waitcnt(0);           // drain LDS writes (wave-local)

            const int npad = (ntot + 7) & ~7;
            float a0 = 0.f, a1 = 0.f;

            uint32 rq0,rq1,rq2,rq3,rq4,rq5,rq6,rq7;
            uint32 hh0,hh1,hh2,hh3,hh4,hh5,hh6,hh7;
            rq0 = qb[0]; hh0 = h2[((rq0 & 0xFFFFu) << 6) + lane];
            rq1 = qb[1]; hh1 = h2[((rq1 & 0xFFFFu) << 6) + lane];
            rq2 = qb[2]; hh2 = h2[((rq2 & 0xFFFFu) << 6) + lane];
            rq3 = qb[3]; hh3 = h2[((rq3 & 0xFFFFu) << 6) + lane];
            rq4 = qb[4]; hh4 = h2[((rq4 & 0xFFFFu) << 6) + lane];
            rq5 = qb[5]; hh5 = h2[((rq5 & 0xFFFFu) << 6) + lane];
            rq6 = qb[6]; hh6 = h2[((rq6 & 0xFFFFu) << 6) + lane];
            rq7 = qb[7]; hh7 = h2[((rq7 & 0xFFFFu) << 6) + lane];

#define CONSUME_PREFETCH(RQ, HH, P)                                          \
    {                                                                        \
        a0 = fmaf(__uint_as_float(RQ & 0xFFFF0000u),                         \
                  __uint_as_float(HH << 16), a0);                            \
        a1 = fmaf(__uint_as_float(RQ & 0xFFFF0000u),                         \
                  __uint_as_float(HH & 0xFFFF0000u), a1);                    \
        uint32 rn = qb[j + 8 + P];                                           \
        RQ = rn; HH = h2[((rn & 0xFFFFu) << 6) + lane];                      \
    }

            for (int j = 0; j < npad; j += 8) {
                CONSUME_PREFETCH(rq0, hh0, 0)
                CONSUME_PREFETCH(rq1, hh1, 1)
                CONSUME_PREFETCH(rq2, hh2, 2)
                CONSUME_PREFETCH(rq3, hh3, 3)
                CONSUME_PREFETCH(rq4, hh4, 4)
                CONSUME_PREFETCH(rq5, hh5, 5)
                CONSUME_PREFETCH(rq6, hh6, 6)
                CONSUME_PREFETCH(rq7, hh7, 7)
            }
#undef CONSUME_PREFETCH

            // overflow list (expected empty)
            int novf = ovf_cnt[0];
            if (novf > OVF_CAP) novf = OVF_CAP;
            for (int k = 0; k < novf; ++k) {
                uint2 e = ovf[k];
                if (e.x == (uint32)r) {
                    uint32 qq = e.y;
                    uint32 hv = h2[((qq & 0xFFFFu) << 6) + lane];
                    a0 = fmaf(__uint_as_float(qq & 0xFFFF0000u), __uint_as_float(hv << 16), a0);
                    a1 = fmaf(__uint_as_float(qq & 0xFFFF0000u), __uint_as_float(hv & 0xFFFF0000u), a1);
                }
            }

            out[(size_t)r * D + lane]      = a0 + bias[lane];
            out[(size_t)r * D + 64 + lane] = a1 + bias[lane + 64];
        }
    }
}

extern "C" void kernel_launch(void* const* d_in, const int* in_sizes, int n_in,
                              void* d_out, int out_size, void* d_ws, size_t ws_size,
                              hipStream_t stream)
{
    const float* x    = (const float*)d_in[0];
    const float* aval = (const float*)d_in[1];
    const float* w    = (const float*)d_in[2];
    const float* bias = (const float*)d_in[3];
    const int* arow   = (const int*)d_in[4];
    const int* acol   = (const int*)d_in[5];

    char* ws = (char*)d_ws;
    uint32* h2     = (uint32*)(ws);               //  2,560,000 B
    int*    cursor = (int*)(ws + 2560000);        //    320,000 B (8 x 10000)
    int*    ovfcnt = (int*)(ws + 2880000);        //          4 B
    int*    bar    = (int*)(ws + 2880004);        //          4 B (grid barrier)
    uint2*  ovf    = (uint2*)(ws + 2880064);      //     65,536 B
    uint32* region = (uint32*)(ws + 2945600);     // 10,240,000 B  (~13.2 MB total)

    hipMemsetAsync(ws + 2560000, 0, 320008, stream);  // cursor + ovf_cnt + bar

    fused_kernel<<<GRID, 256, 0, stream>>>(
        x, w, arow, acol, aval, h2, cursor, ovfcnt, ovf, region,
        bias, (float*)d_out, bar);
}

// Round 2
// 115.852 us; speedup vs baseline: 2.0611x; 2.0611x over previous
//
#include <hip/hip_runtime.h>

#define N_NODES 10000
#define N_EDGES 640000
#define D 128

#define GRID1 1024         // k1: 4 blocks/CU x 256 CUs co-resident
#define GEMM_BLOCKS 157    // 64 nodes per block (MFMA)
#define SCAT_BLOCKS (GRID1 - GEMM_BLOCKS)   // 867 dedicated scatter blocks
#define CAP 32             // per-(row,xcd-group) capacity (mean ~8)
#define OVF_CAP 8192
#define LSTR 136           // LDS row stride in ushorts: 272B, 16B-aligned, 2-way banks
#define QPAD 272           // per-wave flat queue: 256 recs + 16 zero pad

typedef unsigned int uint32;
typedef unsigned short u16;
using short8 = __attribute__((ext_vector_type(8))) short;
using f32x4  = __attribute__((ext_vector_type(4))) float;

__device__ __forceinline__ uint32 f2bf_bits(float f) {
    uint32 u = __float_as_uint(f);
    return (u + 0x7FFFu + ((u >> 16) & 1u)) >> 16;   // RNE bf16 bits
}
__device__ __forceinline__ uint32 pack2(float lo, float hi) {
    return f2bf_bits(lo) | (f2bf_bits(hi) << 16);
}

__device__ __forceinline__ void scat_one(int r, uint32 rc, int s,
                                         int* __restrict__ cursor,
                                         uint32* __restrict__ region,
                                         int* ovf_cnt, uint2* ovf)
{
    int pos = atomicAdd(&cursor[s * N_NODES + r], 1);   // group-private cursor
    if (pos < CAP) {
        // region[row][group][CAP]: 128B cell => 64B lines group-exclusive,
        // writes merge in the issuing XCD's L2.
        region[(r * 8 + s) * CAP + pos] = rc;
    } else {                                   // ~never (Poisson(8) tail), correct
        int o = atomicAdd(ovf_cnt, 1);
        if (o < OVF_CAP) ovf[o] = make_uint2((uint32)r, rc);
    }
}

// R10: split structure restored (R9's software grid barrier cost O(blocks) of
// L2 wb/inv maintenance -- the kernel boundary is the cheap coherence op).
// k1 keeps R9's two good ideas, isolated from the barrier:
//   - blocks [0,157): MFMA GEMM tile, direct global->reg A-fragments (no Xs
//     LDS stage), W staged col-major in LDS. h2 = pack_bf16(x@W).
//   - blocks [157,1024): dedicated scatter, <=1 edge-quad per thread
//     (was ~10 quads at 256 blocks / 1 wave/SIMD -- latency chains, no TLP).
__global__ __launch_bounds__(256, 4) void gemm_scatter_kernel(
    const float* __restrict__ x, const float* __restrict__ w,
    const int* __restrict__ row, const int* __restrict__ col,
    const float* __restrict__ val,
    uint32* __restrict__ h2, int* __restrict__ cursor,
    int* __restrict__ ovf_cnt, uint2* __restrict__ ovf,
    uint32* __restrict__ region)
{
    __shared__ __align__(16) u16 Ws[128 * LSTR];   // 34816 B
    const int t = threadIdx.x;
    const int lane = t & 63;
    const int wid  = t >> 6;

    if (blockIdx.x < GEMM_BLOCKS) {
        // ---- MFMA GEMM: 64 rows/block, 4 waves x 16 rows x 128 cols.
        // A[m=lane&15][k=quad*8+j] loaded DIRECTLY global->reg;
        // B mirrors (k-major per lane) => W staged col-major, each frag one
        // 16B LDS read. C/D: col=lane&15, row=quad*4+reg (HW-verified).
        const int q = lane >> 4, cl = lane & 15;

        #pragma unroll
        for (int i = 0; i < 32; ++i) {                // stage W^T (128x128)
            int lin = t + i * 256;                    // k-pair x col index
            int c = lin & 127;
            int m = lin >> 7;
            float w0 = w[(2 * m) * D + c];
            float w1 = w[(2 * m + 1) * D + c];
            *(uint32*)&Ws[c * LSTR + 2 * m] = pack2(w0, w1);
        }

        int gr = blockIdx.x * 64 + wid * 16 + cl;     // A-fragment row
        if (gr >= N_NODES) gr = N_NODES - 1;          // tail clamp (dup, guarded write)
        const float* xrow = &x[(size_t)gr * D];
        float4 xv[8];
        #pragma unroll
        for (int kk = 0; kk < 4; ++kk) {              // 8 fp32 per k-chunk
            xv[2 * kk]     = *(const float4*)&xrow[kk * 32 + q * 8];
            xv[2 * kk + 1] = *(const float4*)&xrow[kk * 32 + q * 8 + 4];
        }
        __syncthreads();

        f32x4 acc[8] = {};
        #pragma unroll
        for (int kk = 0; kk < 4; ++kk) {
            union { short8 s; uint32 u[4]; } af;
            float4 a = xv[2 * kk], b = xv[2 * kk + 1];
            af.u[0] = pack2(a.x, a.y); af.u[1] = pack2(a.z, a.w);
            af.u[2] = pack2(b.x, b.y); af.u[3] = pack2(b.z, b.w);
            #pragma unroll
            for (int ct = 0; ct < 8; ++ct) {
                short8 bf = *(const short8*)&Ws[(ct * 16 + cl) * LSTR + kk * 32 + q * 8];
                acc[ct] = __builtin_amdgcn_mfma_f32_16x16x32_bf16(af.s, bf, acc[ct], 0, 0, 0);
            }
        }
        // h2[node*64 + c] packs cols (c, c+64): same lane holds tiles ct, ct+4.
        #pragma unroll
        for (int reg = 0; reg < 4; ++reg) {
            int node = blockIdx.x * 64 + wid * 16 + q * 4 + reg;
            if (node < N_NODES) {
                uint32* base = h2 + (size_t)node * 64 + cl;
                #pragma unroll
                for (int ct = 0; ct < 4; ++ct)
                    base[ct * 16] = pack2(acc[ct][reg], acc[ct + 4][reg]);
            }
        }
    } else {
        // ---- Scatter: 867 blocks, 222K threads, 160K quads => <=1 quad/thread
        const int xcc = blockIdx.x & 7;     // round-robin block->XCD locality
        const int tid    = (blockIdx.x - GEMM_BLOCKS) * 256 + t;
        const int stride = SCAT_BLOCKS * 256;
        const int4*   row4 = (const int4*)row;
        const int4*   col4 = (const int4*)col;
        const float4* val4 = (const float4*)val;
        for (int i = tid; i < N_EDGES / 4; i += stride) {
            int4 r = row4[i]; int4 c = col4[i]; float4 v = val4[i];
            scat_one(r.x, (uint32)c.x | (f2bf_bits(v.x) << 16), xcc, cursor, region, ovf_cnt, ovf);
            scat_one(r.y, (uint32)c.y | (f2bf_bits(v.y) << 16), xcc, cursor, region, ovf_cnt, ovf);
            scat_one(r.z, (uint32)c.z | (f2bf_bits(v.z) << 16), xcc, cursor, region, ovf_cnt, ovf);
            scat_one(r.w, (uint32)c.w | (f2bf_bits(v.w) << 16), xcc, cursor, region, ovf_cnt, ovf);
        }
    }
}

// Wave-per-row SpMM (proven R8 body, byte-identical): per-wave LDS compaction
// of the row's 8 segments into a flat list, then a branch-free depth-8
// software-pipelined gather loop (static register rotation, 8 L2 gathers
// always in flight). Zero-pad recs (val bits 0 => fma adds +0.0) kill all
// inner branches. 2500 blocks => 8 blocks/CU, 32 waves/CU; h2 (2.5 MB) is
// L2-resident per XCD after warmup.
__global__ __launch_bounds__(256) void spmm_kernel(
    const uint32* __restrict__ region, const int* __restrict__ cursor,
    const int* __restrict__ ovf_cnt, const uint2* __restrict__ ovf,
    const uint32* __restrict__ h2, const float* __restrict__ bias,
    float* __restrict__ out)
{
    __shared__ uint32 qbuf[4 * QPAD];     // per-wave flat queues (4352 B)
    const int t = threadIdx.x;
    const int lane = t & 63;
    const int wid  = t >> 6;
    const int r = blockIdx.x * 4 + wid;
    uint32* qb = &qbuf[wid * QPAD];

    // preload the row's 1KB region block (segment s = cell>>5, pos = cell&31)
    uint32 rl[4];
    #pragma unroll
    for (int i = 0; i < 4; ++i)
        rl[i] = region[r * 256 + i * 64 + lane];

    // counts + prefix (wave-uniform scalars, computed redundantly per lane)
    int ns[8], pref[9];
    pref[0] = 0;
    #pragma unroll
    for (int s = 0; s < 8; ++s) {
        int c = cursor[s * N_NODES + r];
        ns[s] = (c < CAP) ? c : CAP;
        pref[s + 1] = pref[s] + ns[s];
    }
    const int ntot = pref[8];

    // compact valid recs to flat LDS list; for chunk i lanes<32 are segment
    // 2i (pos=lane&31), lanes>=32 segment 2i+1.
    #pragma unroll
    for (int i = 0; i < 4; ++i) {
        int p  = lane & 31;
        int hi = lane >> 5;                    // 0 or 1
        int n_  = hi ? ns[2 * i + 1]   : ns[2 * i];
        int pf  = hi ? pref[2 * i + 1] : pref[2 * i];
        if (p < n_) qb[pf + p] = rl[i];
    }
    if (lane < 16) qb[ntot + lane] = 0;        // zero pad (val=+0.0 recs)
    __builtin_amdgcn_s_waitcnt(0);             // drain LDS writes (wave-local)

    const int npad = (ntot + 7) & ~7;
    float a0 = 0.f, a1 = 0.f;

    uint32 rq0,rq1,rq2,rq3,rq4,rq5,rq6,rq7;
    uint32 hh0,hh1,hh2,hh3,hh4,hh5,hh6,hh7;
    // preload pipeline (slots always in-bounds thanks to pad)
    rq0 = qb[0]; hh0 = h2[((rq0 & 0xFFFFu) << 6) + lane];
    rq1 = qb[1]; hh1 = h2[((rq1 & 0xFFFFu) << 6) + lane];
    rq2 = qb[2]; hh2 = h2[((rq2 & 0xFFFFu) << 6) + lane];
    rq3 = qb[3]; hh3 = h2[((rq3 & 0xFFFFu) << 6) + lane];
    rq4 = qb[4]; hh4 = h2[((rq4 & 0xFFFFu) << 6) + lane];
    rq5 = qb[5]; hh5 = h2[((rq5 & 0xFFFFu) << 6) + lane];
    rq6 = qb[6]; hh6 = h2[((rq6 & 0xFFFFu) << 6) + lane];
    rq7 = qb[7]; hh7 = h2[((rq7 & 0xFFFFu) << 6) + lane];

#define CONSUME_PREFETCH(RQ, HH, P)                                          \
    {                                                                        \
        a0 = fmaf(__uint_as_float(RQ & 0xFFFF0000u),                         \
                  __uint_as_float(HH << 16), a0);                            \
        a1 = fmaf(__uint_as_float(RQ & 0xFFFF0000u),                         \
                  __uint_as_float(HH & 0xFFFF0000u), a1);                    \
        uint32 rn = qb[j + 8 + P];                                           \
        RQ = rn; HH = h2[((rn & 0xFFFFu) << 6) + lane];                      \
    }

    for (int j = 0; j < npad; j += 8) {
        CONSUME_PREFETCH(rq0, hh0, 0)
        CONSUME_PREFETCH(rq1, hh1, 1)
        CONSUME_PREFETCH(rq2, hh2, 2)
        CONSUME_PREFETCH(rq3, hh3, 3)
        CONSUME_PREFETCH(rq4, hh4, 4)
        CONSUME_PREFETCH(rq5, hh5, 5)
        CONSUME_PREFETCH(rq6, hh6, 6)
        CONSUME_PREFETCH(rq7, hh7, 7)
    }
#undef CONSUME_PREFETCH

    // overflow list (expected empty)
    int novf = ovf_cnt[0];
    if (novf > OVF_CAP) novf = OVF_CAP;
    for (int k = 0; k < novf; ++k) {
        uint2 e = ovf[k];
        if (e.x == (uint32)r) {
            uint32 qq = e.y;
            uint32 hv = h2[((qq & 0xFFFFu) << 6) + lane];
            a0 = fmaf(__uint_as_float(qq & 0xFFFF0000u), __uint_as_float(hv << 16), a0);
            a1 = fmaf(__uint_as_float(qq & 0xFFFF0000u), __uint_as_float(hv & 0xFFFF0000u), a1);
        }
    }

    out[(size_t)r * D + lane]      = a0 + bias[lane];
    out[(size_t)r * D + 64 + lane] = a1 + bias[lane + 64];
}

extern "C" void kernel_launch(void* const* d_in, const int* in_sizes, int n_in,
                              void* d_out, int out_size, void* d_ws, size_t ws_size,
                              hipStream_t stream)
{
    const float* x    = (const float*)d_in[0];
    const float* aval = (const float*)d_in[1];
    const float* w    = (const float*)d_in[2];
    const float* bias = (const float*)d_in[3];
    const int* arow   = (const int*)d_in[4];
    const int* acol   = (const int*)d_in[5];

    char* ws = (char*)d_ws;
    uint32* h2     = (uint32*)(ws);               //  2,560,000 B
    int*    cursor = (int*)(ws + 2560000);        //    320,000 B (8 x 10000)
    int*    ovfcnt = (int*)(ws + 2880000);        //          4 B (+pad)
    uint2*  ovf    = (uint2*)(ws + 2880064);      //     65,536 B
    uint32* region = (uint32*)(ws + 2945600);     // 10,240,000 B  (~13.2 MB)

    hipMemsetAsync(ws + 2560000, 0, 320004, stream);  // cursor + ovf_cnt

    gemm_scatter_kernel<<<GRID1, 256, 0, stream>>>(
        x, w, arow, acol, aval, h2, cursor, ovfcnt, ovf, region);
    spmm_kernel<<<N_NODES / 4, 256, 0, stream>>>(
        region, cursor, ovfcnt, ovf, h2, bias, (float*)d_out);
}